// Round 1
// baseline (374.676 us; speedup 1.0000x reference)
//
#include <hip/hip_runtime.h>
#include <hip/hip_bf16.h>
#include <math.h>

#define B_ 4
#define T_ 4096
#define H_ 16
#define D_ 64
#define C_ 1024
#define BT_ (B_*T_)

using short8  = __attribute__((ext_vector_type(8))) short;
using floatx4 = __attribute__((ext_vector_type(4))) float;

__device__ __forceinline__ float feature_map(float x) {
    return x > 0.0f ? x + 1.0f : __expf(x);   // elu(x)+1
}
__device__ __forceinline__ unsigned short f2bf(float x) {
    union { __hip_bfloat16 b; unsigned short u; } c;
    c.b = __float2bfloat16(x);                 // RNE
    return c.u;
}
__device__ __forceinline__ float bf2f(unsigned short u) {
    union { unsigned int u; float f; } c;
    c.u = (unsigned)u << 16;                   // exact
    return c.f;
}
__device__ __forceinline__ void async16(const void* g, void* l) {
    __builtin_amdgcn_global_load_lds(
        (const __attribute__((address_space(1))) void*)g,
        (__attribute__((address_space(3))) void*)l, 16, 0, 0);
}

// ---------------------------------------------------------------------------
// K0a: x fp32 -> bf16
// ---------------------------------------------------------------------------
__global__ __launch_bounds__(256)
void convert_x_kernel(const float4* __restrict__ x, ushort* __restrict__ xb)
{
    const size_t i = (size_t)blockIdx.x * 256 + threadIdx.x;
    const float4 v = x[i];
    *reinterpret_cast<ushort4*>(&xb[i * 4]) =
        make_ushort4(f2bf(v.x), f2bf(v.y), f2bf(v.z), f2bf(v.w));
}

// ---------------------------------------------------------------------------
// K0b: W[K][N] fp32 -> WT[N][K] bf16
// ---------------------------------------------------------------------------
__global__ __launch_bounds__(256)
void transpose_bf16_kernel(const float* __restrict__ W, ushort* __restrict__ WT,
                           int K, int N)
{
    __shared__ float t[32][33];
    const int n0 = blockIdx.x * 32, k0 = blockIdx.y * 32;
    const int r = threadIdx.x >> 5, c = threadIdx.x & 31;
    #pragma unroll
    for (int i = 0; i < 4; i++)
        t[r + 8 * i][c] = W[(size_t)(k0 + r + 8 * i) * N + n0 + c];
    __syncthreads();
    #pragma unroll
    for (int i = 0; i < 4; i++)
        WT[(size_t)(n0 + r + 8 * i) * K + k0 + c] = f2bf(t[c][r + 8 * i]);
}

// ---------------------------------------------------------------------------
// K1: lean QKV projection GEMM [16384 x 3072] x K=1024, m97-style inner loop.
//     Epilogue (in-register, no extra LDS, no atomics):
//       q-cols: qm[t][c]  = fm((acc+b)/s)       (natural, scalar ushort stores)
//       k-cols: kmT[c][t] = fm((acc+b)/s)       (transposed, ushort4 stores)
//       v-cols: vT[c][t]  = acc+b               (transposed, ushort4 stores)
// ---------------------------------------------------------------------------
__global__ __launch_bounds__(256)
void qkv_mfma_kernel(const ushort* __restrict__ xb, const ushort* __restrict__ WqkvT,
                     const float* __restrict__ bqkv,
                     ushort* __restrict__ qm, ushort* __restrict__ kmT,
                     ushort* __restrict__ vT)
{
    __shared__ __align__(16) unsigned char smem[16384];
    ushort* As = (ushort*)smem;                  // [128][32] bf16
    ushort* Bs = (ushort*)(smem + 8192);         // [128][32] bf16

    const int tid = threadIdx.x;
    const int w = tid >> 6, l = tid & 63;
    const int wm = w >> 1, wn = w & 1;
    const int lr = l & 15, quad = l >> 4;
    const int lk8 = quad * 8;
    const int nBase = blockIdx.x * 128;          // 0..2944 (segment-aligned)
    const int mBase = blockIdx.y * 128;

    const int srow = w * 32 + (l >> 2);
    const int scol = (l & 3) * 8;
    const ushort* gA = xb + (size_t)(mBase + srow) * C_ + scol;
    const ushort* gB = WqkvT + (size_t)(nBase + srow) * C_ + scol;
    void* ldsA = (void*)(smem + w * 2048);
    void* ldsB = (void*)(smem + 8192 + w * 2048);

    floatx4 acc[4][4];
    #pragma unroll
    for (int i = 0; i < 4; i++)
        #pragma unroll
        for (int j = 0; j < 4; j++) acc[i][j] = (floatx4)0.0f;

    for (int k0 = 0; k0 < C_; k0 += 32) {
        __syncthreads();
        async16(gA + k0, ldsA);
        async16(gA + 16 * C_ + k0, (void*)((char*)ldsA + 1024));
        async16(gB + k0, ldsB);
        async16(gB + 16 * C_ + k0, (void*)((char*)ldsB + 1024));
        __syncthreads();

        short8 af[4], bf[4];
        #pragma unroll
        for (int mt = 0; mt < 4; mt++)
            af[mt] = *(const short8*)&As[(wm * 64 + mt * 16 + lr) * 32 + lk8];
        #pragma unroll
        for (int nt = 0; nt < 4; nt++)
            bf[nt] = *(const short8*)&Bs[(wn * 64 + nt * 16 + lr) * 32 + lk8];
        #pragma unroll
        for (int mt = 0; mt < 4; mt++)
            #pragma unroll
            for (int nt = 0; nt < 4; nt++)
                acc[mt][nt] = __builtin_amdgcn_mfma_f32_16x16x32_bf16(
                    af[mt], bf[nt], acc[mt][nt], 0, 0, 0);
    }

    const float inv_scale = 0.35355339059327373f;  // 1/64^0.25
    const int seg = nBase >> 10;                   // 0=q, 1=k, 2=v

    if (seg == 0) {
        // q: natural layout qm[t][c], feature-mapped
        #pragma unroll
        for (int nt = 0; nt < 4; nt++) {
            const int c = nBase + wn * 64 + nt * 16 + lr;
            const float bv = bqkv[c];
            #pragma unroll
            for (int mt = 0; mt < 4; mt++)
                #pragma unroll
                for (int i = 0; i < 4; i++) {
                    const int t = mBase + wm * 64 + mt * 16 + quad * 4 + i;
                    qm[(size_t)t * C_ + c] =
                        f2bf(feature_map((acc[mt][nt][i] + bv) * inv_scale));
                }
        }
    } else {
        // k/v: transposed layout dstT[c][t] (C-fragment is 4 consecutive t per lane)
        ushort* dstT = (seg == 1) ? kmT : vT;
        #pragma unroll
        for (int nt = 0; nt < 4; nt++) {
            const int cfull = nBase + wn * 64 + nt * 16 + lr;   // 1024..3071
            const int c = cfull - (seg << 10);                  // 0..1023
            const float bv = bqkv[cfull];
            #pragma unroll
            for (int mt = 0; mt < 4; mt++) {
                float v0 = acc[mt][nt][0] + bv, v1 = acc[mt][nt][1] + bv;
                float v2 = acc[mt][nt][2] + bv, v3 = acc[mt][nt][3] + bv;
                if (seg == 1) {
                    v0 = feature_map(v0 * inv_scale); v1 = feature_map(v1 * inv_scale);
                    v2 = feature_map(v2 * inv_scale); v3 = feature_map(v3 * inv_scale);
                }
                const int t = mBase + wm * 64 + mt * 16 + quad * 4;
                *(ushort4*)&dstT[(size_t)c * BT_ + t] =
                    make_ushort4(f2bf(v0), f2bf(v1), f2bf(v2), f2bf(v3));
            }
        }
    }
}

// ---------------------------------------------------------------------------
// K2: kv[b,h][d][m] += sum_t km[t][d]*v[t][m]. No LDS: MFMA fragments load
//     straight from row-major kmT/vT (quad*8 k-slices => full 64B lines).
//     grid (tsplit=8, b*h=64); 4 waves = 2x2 output quadrants of 64x64.
// ---------------------------------------------------------------------------
__global__ __launch_bounds__(256)
void kv_accum_kernel(const ushort* __restrict__ kmT, const ushort* __restrict__ vT,
                     float* __restrict__ kv)
{
    const int tid = threadIdx.x;
    const int w = tid >> 6, l = tid & 63;
    const int wm = w >> 1, wn = w & 1;
    const int lr = l & 15, quad = l >> 4;
    const int bh = blockIdx.y;                  // b*16 + h
    const int b = bh >> 4, h = bh & 15;
    const size_t t0 = (size_t)b * T_ + (size_t)blockIdx.x * 512;

    const ushort* Ar = kmT + (size_t)(h * 64 + wm * 32 + lr) * BT_ + t0 + quad * 8;
    const ushort* Br = vT  + (size_t)(h * 64 + wn * 32 + lr) * BT_ + t0 + quad * 8;

    floatx4 acc[2][2];
    #pragma unroll
    for (int i = 0; i < 2; i++)
        #pragma unroll
        for (int j = 0; j < 2; j++) acc[i][j] = (floatx4)0.0f;

    #pragma unroll 4
    for (int tt = 0; tt < 512; tt += 32) {
        const short8 af0 = *(const short8*)&Ar[tt];
        const short8 af1 = *(const short8*)&Ar[(size_t)16 * BT_ + tt];
        const short8 bf0 = *(const short8*)&Br[tt];
        const short8 bf1 = *(const short8*)&Br[(size_t)16 * BT_ + tt];
        acc[0][0] = __builtin_amdgcn_mfma_f32_16x16x32_bf16(af0, bf0, acc[0][0], 0, 0, 0);
        acc[0][1] = __builtin_amdgcn_mfma_f32_16x16x32_bf16(af0, bf1, acc[0][1], 0, 0, 0);
        acc[1][0] = __builtin_amdgcn_mfma_f32_16x16x32_bf16(af1, bf0, acc[1][0], 0, 0, 0);
        acc[1][1] = __builtin_amdgcn_mfma_f32_16x16x32_bf16(af1, bf1, acc[1][1], 0, 0, 0);
    }

    float* kvb = kv + (size_t)bh * (D_ * D_);
    #pragma unroll
    for (int i = 0; i < 2; i++)
        #pragma unroll
        for (int j = 0; j < 2; j++)
            #pragma unroll
            for (int r = 0; r < 4; r++) {
                const int d = wm * 32 + i * 16 + quad * 4 + r;
                const int m = wn * 32 + j * 16 + lr;
                atomicAdd(&kvb[d * 64 + m], acc[i][j][r]);
            }
}

// ---------------------------------------------------------------------------
// K3: out[t][m] = (sum_d qm[t][d] * kv[d][m]) / (z[t]+1e-6), per head.
//     kv^T staged in 9KB LDS (padded); q fragments direct from global
//     (full-line coalesced); z = in-register row-sum of the same q fragments
//     (2x shfl_xor across quads). grid (h=16, tchunk=64); wave = 64 t rows.
// ---------------------------------------------------------------------------
__global__ __launch_bounds__(256)
void pv_kernel(const ushort* __restrict__ qm, const float* __restrict__ kv,
               ushort* __restrict__ attn)
{
    __shared__ ushort kvs[64 * 72];             // kvs[m][d] = kv[d][m], bf16
    const int tid = threadIdx.x;
    const int w = tid >> 6, l = tid & 63;
    const int lr = l & 15, quad = l >> 4;
    const int h = blockIdx.x;
    const int tBase = blockIdx.y * 256;
    const int b = tBase >> 12;

    const float* kvg = kv + ((size_t)b * H_ + h) * (D_ * D_);
    #pragma unroll
    for (int e = 0; e < 4; e++) {
        const int flat = (e * 256 + tid) * 4;   // 4 consecutive m at fixed d
        const float4 vv = *(const float4*)&kvg[flat];
        const int d = flat >> 6, m = flat & 63;
        kvs[(m + 0) * 72 + d] = f2bf(vv.x);
        kvs[(m + 1) * 72 + d] = f2bf(vv.y);
        kvs[(m + 2) * 72 + d] = f2bf(vv.z);
        kvs[(m + 3) * 72 + d] = f2bf(vv.w);
    }
    __syncthreads();

    const int tw = tBase + w * 64;              // this wave's 64 t rows

    floatx4 acc[4][4];                          // [mf][tf]: C row=m, col=t
    #pragma unroll
    for (int i = 0; i < 4; i++)
        #pragma unroll
        for (int j = 0; j < 4; j++) acc[i][j] = (floatx4)0.0f;

    float zp[4] = {0.0f, 0.0f, 0.0f, 0.0f};

    #pragma unroll
    for (int kk = 0; kk < 2; kk++) {
        short8 bf[4];
        #pragma unroll
        for (int tf = 0; tf < 4; tf++) {
            bf[tf] = *(const short8*)&qm[(size_t)(tw + tf * 16 + lr) * C_
                                         + h * 64 + kk * 32 + quad * 8];
            #pragma unroll
            for (int j = 0; j < 8; j++) zp[tf] += bf2f((unsigned short)bf[tf][j]);
        }
        short8 af[4];
        #pragma unroll
        for (int mf = 0; mf < 4; mf++)
            af[mf] = *(const short8*)&kvs[(mf * 16 + lr) * 72 + kk * 32 + quad * 8];
        #pragma unroll
        for (int mf = 0; mf < 4; mf++)
            #pragma unroll
            for (int tf = 0; tf < 4; tf++)
                acc[mf][tf] = __builtin_amdgcn_mfma_f32_16x16x32_bf16(
                    af[mf], bf[tf], acc[mf][tf], 0, 0, 0);
    }

    // z: sum across the 4 quads (each holds a distinct 8-wide d-slice per kk)
    #pragma unroll
    for (int tf = 0; tf < 4; tf++) {
        zp[tf] += __shfl_xor(zp[tf], 16);
        zp[tf] += __shfl_xor(zp[tf], 32);
    }

    #pragma unroll
    for (int tf = 0; tf < 4; tf++) {
        const int t = tw + tf * 16 + lr;
        const float inv = 1.0f / (zp[tf] + 1e-6f);
        #pragma unroll
        for (int mf = 0; mf < 4; mf++) {
            const int m = mf * 16 + quad * 4;
            *(ushort4*)&attn[(size_t)t * C_ + h * 64 + m] =
                make_ushort4(f2bf(acc[mf][tf][0] * inv), f2bf(acc[mf][tf][1] * inv),
                             f2bf(acc[mf][tf][2] * inv), f2bf(acc[mf][tf][3] * inv));
        }
    }
}

// ---------------------------------------------------------------------------
// K4: out-proj [16384x1024]x[1024x1024] bf16-MFMA, +bout, fp32 out
// ---------------------------------------------------------------------------
__global__ __launch_bounds__(256)
void outproj_mfma_kernel(const ushort* __restrict__ attn, const ushort* __restrict__ WoutT,
                         const float* __restrict__ bout, float* __restrict__ out)
{
    __shared__ __align__(16) unsigned char smem[16384];
    ushort* As = (ushort*)smem;
    ushort* Bs = (ushort*)(smem + 8192);

    const int tid = threadIdx.x;
    const int w = tid >> 6, l = tid & 63;
    const int wm = w >> 1, wn = w & 1;
    const int lr = l & 15, lk8 = (l >> 4) * 8;
    const int mBase = blockIdx.y * 128;
    const int nBase = blockIdx.x * 128;

    const int srow = w * 32 + (l >> 2);
    const int scol = (l & 3) * 8;
    const ushort* gA = attn + (size_t)(mBase + srow) * C_ + scol;
    const ushort* gB = WoutT + (size_t)(nBase + srow) * C_ + scol;
    void* ldsA = (void*)(smem + w * 2048);
    void* ldsB = (void*)(smem + 8192 + w * 2048);

    floatx4 acc[4][4];
    #pragma unroll
    for (int i = 0; i < 4; i++)
        #pragma unroll
        for (int j = 0; j < 4; j++) acc[i][j] = (floatx4)0.0f;

    for (int k0 = 0; k0 < C_; k0 += 32) {
        __syncthreads();
        async16(gA + k0, ldsA);
        async16(gA + 16 * C_ + k0, (void*)((char*)ldsA + 1024));
        async16(gB + k0, ldsB);
        async16(gB + 16 * C_ + k0, (void*)((char*)ldsB + 1024));
        __syncthreads();

        short8 af[4], bfr[4];
        #pragma unroll
        for (int mt = 0; mt < 4; mt++)
            af[mt] = *(const short8*)&As[(wm * 64 + mt * 16 + lr) * 32 + lk8];
        #pragma unroll
        for (int nt = 0; nt < 4; nt++)
            bfr[nt] = *(const short8*)&Bs[(wn * 64 + nt * 16 + lr) * 32 + lk8];
        #pragma unroll
        for (int mt = 0; mt < 4; mt++)
            #pragma unroll
            for (int nt = 0; nt < 4; nt++)
                acc[mt][nt] = __builtin_amdgcn_mfma_f32_16x16x32_bf16(
                    af[mt], bfr[nt], acc[mt][nt], 0, 0, 0);
    }

    #pragma unroll
    for (int mt = 0; mt < 4; mt++)
        #pragma unroll
        for (int nt = 0; nt < 4; nt++) {
            const int cc = nBase + wn * 64 + nt * 16 + lr;
            const float bv = bout[cc];
            #pragma unroll
            for (int i = 0; i < 4; i++) {
                const int rr = mBase + wm * 64 + mt * 16 + (l >> 4) * 4 + i;
                out[(size_t)rr * C_ + cc] = acc[mt][nt][i] + bv;
            }
        }
}

// ---------------------------------------------------------------------------
// Workspace map (fits exactly in the prior 76,546,048 B footprint):
//   ws:    xb[33.5M | aliased as attn after K1] | WqkvT 6.3M | WoutT 2M |
//          vT 33.5M | kv 1M
//   d_out: qm 33.5M | kmT 33.5M   (both dead before K4 writes out)
// ---------------------------------------------------------------------------
extern "C" void kernel_launch(void* const* d_in, const int* in_sizes, int n_in,
                              void* d_out, int out_size, void* d_ws, size_t ws_size,
                              hipStream_t stream)
{
    const float* x    = (const float*)d_in[0];
    const float* Wqkv = (const float*)d_in[1];
    const float* bqkv = (const float*)d_in[2];
    const float* Wout = (const float*)d_in[3];
    const float* bout = (const float*)d_in[4];
    float* out = (float*)d_out;

    char* ws = (char*)d_ws;
    ushort* xb     = (ushort*)ws;                       // 33,554,432 B
    ushort* WqkvT  = (ushort*)(ws + 33554432);          //  6,291,456 B
    ushort* WoutT  = (ushort*)(ws + 39845888);          //  2,097,152 B
    ushort* vT     = (ushort*)(ws + 41943040);          // 33,554,432 B
    float*  kv     = (float*) (ws + 75497472);          //  1,048,576 B
    ushort* attn   = (ushort*)ws;                       // alias of xb (dead after K1)
    ushort* qm     = (ushort*)d_out;                    // scratch in d_out
    ushort* kmT    = (ushort*)((char*)d_out + 33554432);

    hipMemsetAsync(kv, 0, (size_t)B_ * H_ * D_ * D_ * sizeof(float), stream);

    convert_x_kernel<<<(BT_ * C_ / 4) / 256, 256, 0, stream>>>((const float4*)x, xb);
    transpose_bf16_kernel<<<dim3(3 * C_ / 32, C_ / 32), 256, 0, stream>>>(Wqkv, WqkvT, C_, 3 * C_);
    transpose_bf16_kernel<<<dim3(C_ / 32, C_ / 32), 256, 0, stream>>>(Wout, WoutT, C_, C_);

    qkv_mfma_kernel<<<dim3(3 * C_ / 128, BT_ / 128), 256, 0, stream>>>(
        xb, WqkvT, bqkv, qm, kmT, vT);
    kv_accum_kernel<<<dim3(8, B_ * H_), 256, 0, stream>>>(kmT, vT, kv);
    pv_kernel<<<dim3(H_, BT_ / 256), 256, 0, stream>>>(qm, kv, attn);
    outproj_mfma_kernel<<<dim3(C_ / 128, BT_ / 128), 256, 0, stream>>>(attn, WoutT, bout, out);
}

// Round 3
// 315.227 us; speedup vs baseline: 1.1886x; 1.1886x over previous
//
#include <hip/hip_runtime.h>
#include <hip/hip_bf16.h>
#include <math.h>

#define B_ 4
#define T_ 4096
#define H_ 16
#define D_ 64
#define C_ 1024
#define BT_ (B_*T_)

using short8  = __attribute__((ext_vector_type(8))) short;
using floatx4 = __attribute__((ext_vector_type(4))) float;

__device__ __forceinline__ float feature_map(float x) {
    return x > 0.0f ? x + 1.0f : __expf(x);   // elu(x)+1
}
__device__ __forceinline__ unsigned short f2bf(float x) {
    union { __hip_bfloat16 b; unsigned short u; } c;
    c.b = __float2bfloat16(x);                 // RNE
    return c.u;
}
__device__ __forceinline__ float bf2f(unsigned short u) {
    union { unsigned int u; float f; } c;
    c.u = (unsigned)u << 16;                   // exact
    return c.f;
}
__device__ __forceinline__ void async16(const void* g, void* l) {
    __builtin_amdgcn_global_load_lds(
        (const __attribute__((address_space(1))) void*)g,
        (__attribute__((address_space(3))) void*)l, 16, 0, 0);
}

// ---------------------------------------------------------------------------
// K0a: x fp32 -> bf16
// ---------------------------------------------------------------------------
__global__ __launch_bounds__(256)
void convert_x_kernel(const float4* __restrict__ x, ushort* __restrict__ xb)
{
    const size_t i = (size_t)blockIdx.x * 256 + threadIdx.x;
    const float4 v = x[i];
    *reinterpret_cast<ushort4*>(&xb[i * 4]) =
        make_ushort4(f2bf(v.x), f2bf(v.y), f2bf(v.z), f2bf(v.w));
}

// ---------------------------------------------------------------------------
// K0b: W[K][N] fp32 -> WT[N][K] bf16
// ---------------------------------------------------------------------------
__global__ __launch_bounds__(256)
void transpose_bf16_kernel(const float* __restrict__ W, ushort* __restrict__ WT,
                           int K, int N)
{
    __shared__ float t[32][33];
    const int n0 = blockIdx.x * 32, k0 = blockIdx.y * 32;
    const int r = threadIdx.x >> 5, c = threadIdx.x & 31;
    #pragma unroll
    for (int i = 0; i < 4; i++)
        t[r + 8 * i][c] = W[(size_t)(k0 + r + 8 * i) * N + n0 + c];
    __syncthreads();
    #pragma unroll
    for (int i = 0; i < 4; i++)
        WT[(size_t)(n0 + r + 8 * i) * K + k0 + c] = f2bf(t[c][r + 8 * i]);
}

// ---------------------------------------------------------------------------
// 256x256x(K=1024) bf16 8-phase GEMM (T2+T3+T4+T5), B^T operands.
//   LDS: A [buf][half][128 rows][64 k] + B same, 128 KiB total.
//   A half h, row s(0..127): tile row = (s>>6)*128 + h*64 + (s&63)   (wm-split)
//   B half h, row s(0..127): tile row = (s>>5)*64  + h*32 + (s&31)   (wn-split)
//   Swizzle (both sides, involution): byte ^= ((row&7)<<4)
//   Stage order/iter: p1 A1(t+1)|b1, p2 A0(t+2)|b0, p3 B0(t+2)|b0,
//     p4 B1(t+2)|b0 +vm6, p5 A1(t+2)|b0, p6 A0(t+3)|b1, p7 B0(t+3)|b1,
//     p8 B1(t+3)|b1 +vm6.   (every staged region's last read retired >=1
//     phase earlier; vmcnt(6)=3 half-tiles in flight publishes tile t+1/t+2)
//   EPI 0: QKV epilogue (q natural fm / k^T fm / v^T).  EPI 1: +bias fp32.
// ---------------------------------------------------------------------------
#define BAR()    __builtin_amdgcn_s_barrier()
#define WAITDS() do { asm volatile("s_waitcnt lgkmcnt(0)" ::: "memory"); \
                      __builtin_amdgcn_sched_barrier(0); } while(0)
#define VM6()    do { asm volatile("s_waitcnt vmcnt(6)" ::: "memory"); \
                      __builtin_amdgcn_sched_barrier(0); } while(0)

#define LDA(slot, mf, ks, buf) \
    aR[slot][ks] = *(const short8*)(smem + (buf)*32768 + ((mf)>>2)*16384 + \
                                    aRowB + ((mf)&3)*2048 + cks##ks)
#define LDB(nf, ks, buf) \
    bR[nf][ks] = *(const short8*)(smem + 65536 + (buf)*32768 + ((nf)>>1)*16384 + \
                                  bRowB + ((nf)&1)*2048 + cks##ks)
#define LDA8(MB, BUF) do { \
    LDA(0, MB+0, 0, BUF); LDA(0, MB+0, 1, BUF); \
    LDA(1, MB+1, 0, BUF); LDA(1, MB+1, 1, BUF); \
    LDA(2, MB+2, 0, BUF); LDA(2, MB+2, 1, BUF); \
    LDA(3, MB+3, 0, BUF); LDA(3, MB+3, 1, BUF); } while(0)
#define LDB4(NF, BUF) do { \
    LDB(NF+0, 0, BUF); LDB(NF+0, 1, BUF); \
    LDB(NF+1, 0, BUF); LDB(NF+1, 1, BUF); } while(0)

#define MM(mf, nf, ks, slot) \
    acc[mf][nf] = __builtin_amdgcn_mfma_f32_16x16x32_bf16( \
        aR[slot][ks], bR[nf][ks], acc[mf][nf], 0, 0, 0)
#define MFMAQ(MB, NF) do { \
    MM(MB+0,NF+0,0,0); MM(MB+1,NF+0,0,1); MM(MB+2,NF+0,0,2); MM(MB+3,NF+0,0,3); \
    MM(MB+0,NF+1,0,0); MM(MB+1,NF+1,0,1); MM(MB+2,NF+1,0,2); MM(MB+3,NF+1,0,3); \
    MM(MB+0,NF+0,1,0); MM(MB+1,NF+0,1,1); MM(MB+2,NF+0,1,2); MM(MB+3,NF+0,1,3); \
    MM(MB+0,NF+1,1,0); MM(MB+1,NF+1,1,1); MM(MB+2,NF+1,1,2); MM(MB+3,NF+1,1,3); \
} while(0)

#define STG(SRC, OPB, h, w, buf) do { \
    async16(SRC[h][0] + (size_t)(w)*128, \
            smem + (OPB) + (buf)*32768 + (h)*16384 + wv*1024); \
    async16(SRC[h][1] + (size_t)(w)*128, \
            smem + (OPB) + (buf)*32768 + (h)*16384 + 8192 + wv*1024); \
} while(0)

template<int EPI, int NBX>
__global__ __launch_bounds__(512, 2)
void gemm256_8ph(const ushort* __restrict__ A, const ushort* __restrict__ Bm,
                 const float* __restrict__ bias,
                 ushort* __restrict__ q_out, ushort* __restrict__ kT_out,
                 ushort* __restrict__ vT_out, float* __restrict__ f_out)
{
    __shared__ __align__(16) unsigned char smem[131072];

    const int tid = threadIdx.x;
    const int wv = tid >> 6, l = tid & 63;
    const int wm = wv >> 2, wn = wv & 3;
    const int lr = l & 15, quad = l >> 4;

    // XCD-aware swizzle (grid % 8 == 0 for both instantiations)
    int wg = blockIdx.x;
    { const int cpx = (int)gridDim.x >> 3; wg = (wg & 7) * cpx + (wg >> 3); }
    const int mb = wg / NBX, nb = wg % NBX;
    const int mBase = mb * 256, nBase = nb * 256;

    // ---- staging source offsets (swizzled global src, linear LDS dest)
    const int s0 = tid >> 3;                               // 0..63
    const int cb = ((tid & 7) * 16) ^ ((s0 & 7) << 4);
    const char* Abyte = (const char*)(A + (size_t)mBase * C_);
    const char* Bbyte = (const char*)(Bm + (size_t)nBase * C_);
    const char* aSrc[2][2]; const char* bSrc[2][2];
    #pragma unroll
    for (int h = 0; h < 2; h++) {
        aSrc[h][0] = Abyte + (size_t)(h * 64 + s0) * 2048 + cb;
        aSrc[h][1] = Abyte + (size_t)(128 + h * 64 + s0) * 2048 + cb;
        const int bq = (s0 >> 5) * 64 + h * 32 + (s0 & 31);
        bSrc[h][0] = Bbyte + (size_t)bq * 2048 + cb;
        bSrc[h][1] = Bbyte + (size_t)(bq + 128) * 2048 + cb;
    }

    // ---- ds_read fragment addressing (swizzled)
    const int aRowB = (wm * 64 + lr) * 128;
    const int bRowB = (wn * 32 + lr) * 128;
    const int cks0 = (quad * 16) ^ ((lr & 7) << 4);
    const int cks1 = 64 ^ cks0;

    floatx4 acc[8][4];
    #pragma unroll
    for (int i = 0; i < 8; i++)
        #pragma unroll
        for (int j = 0; j < 4; j++) acc[i][j] = (floatx4)0.0f;
    short8 aR[4][2], bR[4][2];

    // ---- prologue: 7 half-tiles, keep 3 in flight
    STG(aSrc,     0, 0, 0, 0);   // A0(0)
    STG(bSrc, 65536, 0, 0, 0);   // B0(0)
    STG(bSrc, 65536, 1, 0, 0);   // B1(0)
    STG(aSrc,     0, 1, 0, 0);   // A1(0)
    STG(aSrc,     0, 0, 1, 1);   // A0(1)
    STG(bSrc, 65536, 0, 1, 1);   // B0(1)
    STG(bSrc, 65536, 1, 1, 1);   // B1(1)
    asm volatile("s_waitcnt vmcnt(6)" ::: "memory");
    __builtin_amdgcn_sched_barrier(0);
    BAR();

    #pragma unroll 1
    for (int it = 0; it < 8; ++it) {
        const int t1v = 2 * it + 1;
        const int t2v = (2 * it + 2) & 15;    // wrap-staged tail (exact counts)
        const int t3v = (2 * it + 3) & 15;
        // p1: quad(0,0) of tile 2it (buf0)
        LDA8(0, 0); LDB4(0, 0);
        STG(aSrc, 0, 1, t1v, 1);
        BAR(); WAITDS(); __builtin_amdgcn_s_setprio(1); MFMAQ(0, 0);
        __builtin_amdgcn_s_setprio(0); BAR();
        // p2: quad(0,1)
        LDB4(2, 0);
        STG(aSrc, 0, 0, t2v, 0);
        BAR(); WAITDS(); __builtin_amdgcn_s_setprio(1); MFMAQ(0, 2);
        __builtin_amdgcn_s_setprio(0); BAR();
        // p3: quad(1,1)
        LDA8(4, 0);
        STG(bSrc, 65536, 0, t2v, 0);
        BAR(); WAITDS(); __builtin_amdgcn_s_setprio(1); MFMAQ(4, 2);
        __builtin_amdgcn_s_setprio(0); BAR();
        // p4: quad(1,0); publish tile 2it+1
        STG(bSrc, 65536, 1, t2v, 0);
        BAR(); WAITDS(); __builtin_amdgcn_s_setprio(1); MFMAQ(4, 0);
        __builtin_amdgcn_s_setprio(0); VM6(); BAR();
        // p5: quad(0,0) of tile 2it+1 (buf1)
        LDA8(0, 1); LDB4(0, 1);
        STG(aSrc, 0, 1, t2v, 0);
        BAR(); WAITDS(); __builtin_amdgcn_s_setprio(1); MFMAQ(0, 0);
        __builtin_amdgcn_s_setprio(0); BAR();
        // p6: quad(0,1)
        LDB4(2, 1);
        STG(aSrc, 0, 0, t3v, 1);
        BAR(); WAITDS(); __builtin_amdgcn_s_setprio(1); MFMAQ(0, 2);
        __builtin_amdgcn_s_setprio(0); BAR();
        // p7: quad(1,1)
        LDA8(4, 1);
        STG(bSrc, 65536, 0, t3v, 1);
        BAR(); WAITDS(); __builtin_amdgcn_s_setprio(1); MFMAQ(4, 2);
        __builtin_amdgcn_s_setprio(0); BAR();
        // p8: quad(1,0); publish tile 2it+2
        STG(bSrc, 65536, 1, t3v, 1);
        BAR(); WAITDS(); __builtin_amdgcn_s_setprio(1); MFMAQ(4, 0);
        __builtin_amdgcn_s_setprio(0); VM6(); BAR();
    }

    // ---- epilogue (in-register)
    if (EPI == 0) {
        const float inv_scale = 0.35355339059327373f;  // 1/64^0.25
        const int seg = nBase >> 10;                   // 0=q, 1=k, 2=v
        if (seg == 0) {
            #pragma unroll
            for (int nf = 0; nf < 4; nf++) {
                const int c = nBase + wn * 64 + nf * 16 + lr;
                const float bv = bias[c];
                #pragma unroll
                for (int mf = 0; mf < 8; mf++)
                    #pragma unroll
                    for (int i = 0; i < 4; i++) {
                        const int t = mBase + wm * 128 + mf * 16 + quad * 4 + i;
                        q_out[(size_t)t * C_ + c] =
                            f2bf(feature_map((acc[mf][nf][i] + bv) * inv_scale));
                    }
            }
        } else {
            ushort* dstT = (seg == 1) ? kT_out : vT_out;
            #pragma unroll
            for (int nf = 0; nf < 4; nf++) {
                const int cfull = nBase + wn * 64 + nf * 16 + lr;
                const int c = cfull & 1023;
                const float bv = bias[cfull];
                #pragma unroll
                for (int mf = 0; mf < 8; mf++) {
                    float v0 = acc[mf][nf][0] + bv, v1 = acc[mf][nf][1] + bv;
                    float v2 = acc[mf][nf][2] + bv, v3 = acc[mf][nf][3] + bv;
                    if (seg == 1) {
                        v0 = feature_map(v0 * inv_scale); v1 = feature_map(v1 * inv_scale);
                        v2 = feature_map(v2 * inv_scale); v3 = feature_map(v3 * inv_scale);
                    }
                    const int tt = mBase + wm * 128 + mf * 16 + quad * 4;
                    *(ushort4*)&dstT[(size_t)c * BT_ + tt] =
                        make_ushort4(f2bf(v0), f2bf(v1), f2bf(v2), f2bf(v3));
                }
            }
        }
    } else {
        #pragma unroll
        for (int nf = 0; nf < 4; nf++) {
            const int c = nBase + wn * 64 + nf * 16 + lr;
            const float bv = bias[c];
            #pragma unroll
            for (int mf = 0; mf < 8; mf++)
                #pragma unroll
                for (int i = 0; i < 4; i++) {
                    const int row = mBase + wm * 128 + mf * 16 + quad * 4 + i;
                    f_out[(size_t)row * C_ + c] = acc[mf][nf][i] + bv;
                }
        }
    }
    asm volatile("s_waitcnt vmcnt(0)" ::: "memory");   // drain wrap-staged loads
}

// ---------------------------------------------------------------------------
// K2: kv[b,h][d][m] += sum_t km[t][d]*v[t][m]. No LDS: MFMA fragments load
//     straight from row-major kmT/vT; grid (tsplit=8, b*h=64).
// ---------------------------------------------------------------------------
__global__ __launch_bounds__(256)
void kv_accum_kernel(const ushort* __restrict__ kmT, const ushort* __restrict__ vT,
                     float* __restrict__ kv)
{
    const int tid = threadIdx.x;
    const int w = tid >> 6, l = tid & 63;
    const int wm = w >> 1, wn = w & 1;
    const int lr = l & 15, quad = l >> 4;
    const int bh = blockIdx.y;                  // b*16 + h
    const int b = bh >> 4, h = bh & 15;
    const size_t t0 = (size_t)b * T_ + (size_t)blockIdx.x * 512;

    const ushort* Ar = kmT + (size_t)(h * 64 + wm * 32 + lr) * BT_ + t0 + quad * 8;
    const ushort* Br = vT  + (size_t)(h * 64 + wn * 32 + lr) * BT_ + t0 + quad * 8;

    floatx4 acc[2][2];
    #pragma unroll
    for (int i = 0; i < 2; i++)
        #pragma unroll
        for (int j = 0; j < 2; j++) acc[i][j] = (floatx4)0.0f;

    #pragma unroll 4
    for (int tt = 0; tt < 512; tt += 32) {
        const short8 af0 = *(const short8*)&Ar[tt];
        const short8 af1 = *(const short8*)&Ar[(size_t)16 * BT_ + tt];
        const short8 bf0 = *(const short8*)&Br[tt];
        const short8 bf1 = *(const short8*)&Br[(size_t)16 * BT_ + tt];
        acc[0][0] = __builtin_amdgcn_mfma_f32_16x16x32_bf16(af0, bf0, acc[0][0], 0, 0, 0);
        acc[0][1] = __builtin_amdgcn_mfma_f32_16x16x32_bf16(af0, bf1, acc[0][1], 0, 0, 0);
        acc[1][0] = __builtin_amdgcn_mfma_f32_16x16x32_bf16(af1, bf0, acc[1][0], 0, 0, 0);
        acc[1][1] = __builtin_amdgcn_mfma_f32_16x16x32_bf16(af1, bf1, acc[1][1], 0, 0, 0);
    }

    float* kvb = kv + (size_t)bh * (D_ * D_);
    #pragma unroll
    for (int i = 0; i < 2; i++)
        #pragma unroll
        for (int j = 0; j < 2; j++)
            #pragma unroll
            for (int r = 0; r < 4; r++) {
                const int d = wm * 32 + i * 16 + quad * 4 + r;
                const int m = wn * 32 + j * 16 + lr;
                atomicAdd(&kvb[d * 64 + m], acc[i][j][r]);
            }
}

// ---------------------------------------------------------------------------
// K3: out[t][m] = (sum_d qm[t][d] * kv[d][m]) / (z[t]+1e-6), per head.
// ---------------------------------------------------------------------------
__global__ __launch_bounds__(256)
void pv_kernel(const ushort* __restrict__ qm, const float* __restrict__ kv,
               ushort* __restrict__ attn)
{
    __shared__ ushort kvs[64 * 72];             // kvs[m][d] = kv[d][m], bf16
    const int tid = threadIdx.x;
    const int w = tid >> 6, l = tid & 63;
    const int lr = l & 15, quad = l >> 4;
    const int h = blockIdx.x;
    const int tBase = blockIdx.y * 256;
    const int b = tBase >> 12;

    const float* kvg = kv + ((size_t)b * H_ + h) * (D_ * D_);
    #pragma unroll
    for (int e = 0; e < 4; e++) {
        const int flat = (e * 256 + tid) * 4;
        const float4 vv = *(const float4*)&kvg[flat];
        const int d = flat >> 6, m = flat & 63;
        kvs[(m + 0) * 72 + d] = f2bf(vv.x);
        kvs[(m + 1) * 72 + d] = f2bf(vv.y);
        kvs[(m + 2) * 72 + d] = f2bf(vv.z);
        kvs[(m + 3) * 72 + d] = f2bf(vv.w);
    }
    __syncthreads();

    const int tw = tBase + w * 64;

    floatx4 acc[4][4];                          // [mf][tf]: C row=m, col=t
    #pragma unroll
    for (int i = 0; i < 4; i++)
        #pragma unroll
        for (int j = 0; j < 4; j++) acc[i][j] = (floatx4)0.0f;

    float zp[4] = {0.0f, 0.0f, 0.0f, 0.0f};

    #pragma unroll
    for (int kk = 0; kk < 2; kk++) {
        short8 bf[4];
        #pragma unroll
        for (int tf = 0; tf < 4; tf++) {
            bf[tf] = *(const short8*)&qm[(size_t)(tw + tf * 16 + lr) * C_
                                         + h * 64 + kk * 32 + quad * 8];
            #pragma unroll
            for (int j = 0; j < 8; j++) zp[tf] += bf2f((unsigned short)bf[tf][j]);
        }
        short8 af[4];
        #pragma unroll
        for (int mf = 0; mf < 4; mf++)
            af[mf] = *(const short8*)&kvs[(mf * 16 + lr) * 72 + kk * 32 + quad * 8];
        #pragma unroll
        for (int mf = 0; mf < 4; mf++)
            #pragma unroll
            for (int tf = 0; tf < 4; tf++)
                acc[mf][tf] = __builtin_amdgcn_mfma_f32_16x16x32_bf16(
                    af[mf], bf[tf], acc[mf][tf], 0, 0, 0);
    }

    #pragma unroll
    for (int tf = 0; tf < 4; tf++) {
        zp[tf] += __shfl_xor(zp[tf], 16);
        zp[tf] += __shfl_xor(zp[tf], 32);
    }

    #pragma unroll
    for (int tf = 0; tf < 4; tf++) {
        const int t = tw + tf * 16 + lr;
        const float inv = 1.0f / (zp[tf] + 1e-6f);
        #pragma unroll
        for (int mf = 0; mf < 4; mf++) {
            const int m = mf * 16 + quad * 4;
            *(ushort4*)&attn[(size_t)t * C_ + h * 64 + m] =
                make_ushort4(f2bf(acc[mf][tf][0] * inv), f2bf(acc[mf][tf][1] * inv),
                             f2bf(acc[mf][tf][2] * inv), f2bf(acc[mf][tf][3] * inv));
        }
    }
}

// ---------------------------------------------------------------------------
// Workspace map:
//   ws:    xb 33.5M (aliased as attn after QKV) | WqkvT 6.3M | WoutT 2M |
//          vT 33.5M | kv 1M
//   d_out: qm 33.5M | kmT 33.5M   (both dead before outproj writes out)
// ---------------------------------------------------------------------------
extern "C" void kernel_launch(void* const* d_in, const int* in_sizes, int n_in,
                              void* d_out, int out_size, void* d_ws, size_t ws_size,
                              hipStream_t stream)
{
    const float* x    = (const float*)d_in[0];
    const float* Wqkv = (const float*)d_in[1];
    const float* bqkv = (const float*)d_in[2];
    const float* Wout = (const float*)d_in[3];
    const float* bout = (const float*)d_in[4];
    float* out = (float*)d_out;

    char* ws = (char*)d_ws;
    ushort* xb     = (ushort*)ws;                       // 33,554,432 B
    ushort* WqkvT  = (ushort*)(ws + 33554432);          //  6,291,456 B
    ushort* WoutT  = (ushort*)(ws + 39845888);          //  2,097,152 B
    ushort* vT     = (ushort*)(ws + 41943040);          // 33,554,432 B
    float*  kv     = (float*) (ws + 75497472);          //  1,048,576 B
    ushort* attn   = (ushort*)ws;                       // alias of xb
    ushort* qm     = (ushort*)d_out;                    // scratch in d_out
    ushort* kmT    = (ushort*)((char*)d_out + 33554432);

    hipMemsetAsync(kv, 0, (size_t)B_ * H_ * D_ * D_ * sizeof(float), stream);

    convert_x_kernel<<<(BT_ * C_ / 4) / 256, 256, 0, stream>>>((const float4*)x, xb);
    transpose_bf16_kernel<<<dim3(3 * C_ / 32, C_ / 32), 256, 0, stream>>>(Wqkv, WqkvT, C_, 3 * C_);
    transpose_bf16_kernel<<<dim3(C_ / 32, C_ / 32), 256, 0, stream>>>(Wout, WoutT, C_, C_);

    gemm256_8ph<0, 12><<<dim3(768), 512, 0, stream>>>(
        xb, WqkvT, bqkv, qm, kmT, vT, nullptr);
    kv_accum_kernel<<<dim3(8, B_ * H_), 256, 0, stream>>>(kmT, vT, kv);
    pv_kernel<<<dim3(H_, BT_ / 256), 256, 0, stream>>>(qm, kv, attn);
    gemm256_8ph<1, 4><<<dim3(256), 512, 0, stream>>>(
        attn, WoutT, bout, nullptr, nullptr, nullptr, out);
}

// Round 4
// 312.128 us; speedup vs baseline: 1.2004x; 1.0099x over previous
//
#include <hip/hip_runtime.h>
#include <hip/hip_bf16.h>
#include <math.h>

#define B_ 4
#define T_ 4096
#define H_ 16
#define D_ 64
#define C_ 1024
#define BT_ (B_*T_)

using short8  = __attribute__((ext_vector_type(8))) short;
using floatx4 = __attribute__((ext_vector_type(4))) float;

__device__ __forceinline__ float feature_map(float x) {
    return x > 0.0f ? x + 1.0f : __expf(x);   // elu(x)+1
}
__device__ __forceinline__ unsigned short f2bf(float x) {
    union { __hip_bfloat16 b; unsigned short u; } c;
    c.b = __float2bfloat16(x);                 // RNE
    return c.u;
}
__device__ __forceinline__ float bf2f(unsigned short u) {
    union { unsigned int u; float f; } c;
    c.u = (unsigned)u << 16;                   // exact
    return c.f;
}
__device__ __forceinline__ void async16(const void* g, void* l) {
    __builtin_amdgcn_global_load_lds(
        (const __attribute__((address_space(1))) void*)g,
        (__attribute__((address_space(3))) void*)l, 16, 0, 0);
}
__device__ __forceinline__ const char* sel3(const char* a0, const char* a1,
                                            const char* a2, int t) {
    return t == 0 ? a0 : (t == 1 ? a1 : a2);
}

// ---------------------------------------------------------------------------
// K0a: x fp32 -> bf16 (8 elems/thread, 16B stores)
// ---------------------------------------------------------------------------
__global__ __launch_bounds__(256)
void convert_x_kernel(const float4* __restrict__ x, ushort* __restrict__ xb)
{
    const size_t i = ((size_t)blockIdx.x * 256 + threadIdx.x) * 2;
    const float4 a = x[i], b = x[i + 1];
    short8 r;
    r[0] = (short)f2bf(a.x); r[1] = (short)f2bf(a.y);
    r[2] = (short)f2bf(a.z); r[3] = (short)f2bf(a.w);
    r[4] = (short)f2bf(b.x); r[5] = (short)f2bf(b.y);
    r[6] = (short)f2bf(b.z); r[7] = (short)f2bf(b.w);
    *reinterpret_cast<short8*>(&xb[i * 4]) = r;
}

// ---------------------------------------------------------------------------
// K0b: W[K][N] fp32 -> WT[N][K] bf16
// ---------------------------------------------------------------------------
__global__ __launch_bounds__(256)
void transpose_bf16_kernel(const float* __restrict__ W, ushort* __restrict__ WT,
                           int K, int N)
{
    __shared__ float t[32][33];
    const int n0 = blockIdx.x * 32, k0 = blockIdx.y * 32;
    const int r = threadIdx.x >> 5, c = threadIdx.x & 31;
    #pragma unroll
    for (int i = 0; i < 4; i++)
        t[r + 8 * i][c] = W[(size_t)(k0 + r + 8 * i) * N + n0 + c];
    __syncthreads();
    #pragma unroll
    for (int i = 0; i < 4; i++)
        WT[(size_t)(n0 + r + 8 * i) * K + k0 + c] = f2bf(t[c][r + 8 * i]);
}

// ---------------------------------------------------------------------------
// 256x256x(K=1024) bf16 8-phase GEMM (T1+T2+T3+T4+T5), B^T operands,
// PERSISTENT: each block chains NTILE output tiles through ONE pipeline
// (staging schedule is a pure function of global K-step; 16 steps/tile keeps
// buffer parity; epilogue is register->global only, between tiles).
// ---------------------------------------------------------------------------
#define BAR()    __builtin_amdgcn_s_barrier()
#define WAITDS() do { asm volatile("s_waitcnt lgkmcnt(0)" ::: "memory"); \
                      __builtin_amdgcn_sched_barrier(0); } while(0)
#define VM6()    do { asm volatile("s_waitcnt vmcnt(6)" ::: "memory"); \
                      __builtin_amdgcn_sched_barrier(0); } while(0)

#define LDA(slot, mf, ks, buf) \
    aR[slot][ks] = *(const short8*)(smem + (buf)*32768 + ((mf)>>2)*16384 + \
                                    aRowB + ((mf)&3)*2048 + cks##ks)
#define LDB(nf, ks, buf) \
    bR[nf][ks] = *(const short8*)(smem + 65536 + (buf)*32768 + ((nf)>>1)*16384 + \
                                  bRowB + ((nf)&1)*2048 + cks##ks)
#define LDA8(MB, BUF) do { \
    LDA(0, MB+0, 0, BUF); LDA(0, MB+0, 1, BUF); \
    LDA(1, MB+1, 0, BUF); LDA(1, MB+1, 1, BUF); \
    LDA(2, MB+2, 0, BUF); LDA(2, MB+2, 1, BUF); \
    LDA(3, MB+3, 0, BUF); LDA(3, MB+3, 1, BUF); } while(0)
#define LDB4(NF, BUF) do { \
    LDB(NF+0, 0, BUF); LDB(NF+0, 1, BUF); \
    LDB(NF+1, 0, BUF); LDB(NF+1, 1, BUF); } while(0)

#define MM(mf, nf, ks, slot) \
    acc[mf][nf] = __builtin_amdgcn_mfma_f32_16x16x32_bf16( \
        aR[slot][ks], bR[nf][ks], acc[mf][nf], 0, 0, 0)
#define MFMAQ(MB, NF) do { \
    MM(MB+0,NF+0,0,0); MM(MB+1,NF+0,0,1); MM(MB+2,NF+0,0,2); MM(MB+3,NF+0,0,3); \
    MM(MB+0,NF+1,0,0); MM(MB+1,NF+1,0,1); MM(MB+2,NF+1,0,2); MM(MB+3,NF+1,0,3); \
    MM(MB+0,NF+0,1,0); MM(MB+1,NF+0,1,1); MM(MB+2,NF+0,1,2); MM(MB+3,NF+0,1,3); \
    MM(MB+0,NF+1,1,0); MM(MB+1,NF+1,1,1); MM(MB+2,NF+1,1,2); MM(MB+3,NF+1,1,3); \
} while(0)

// staged address = tile-base (by global step G) + per-thread row offset + (G&15)*128
#define STGA(h, G, buf) do { int _g = (G); if (_g >= NTILE*16) _g -= NTILE*16; \
    const char* _b = sel3(Ab0, Ab1, Ab2, _g >> 4); const int _w = (_g & 15) * 128; \
    async16(_b + aOf##h##0 + _w, smem + (buf)*32768 + (h)*16384 + wv*1024); \
    async16(_b + aOf##h##1 + _w, smem + (buf)*32768 + (h)*16384 + 8192 + wv*1024); \
} while(0)
#define STGB(h, G, buf) do { int _g = (G); if (_g >= NTILE*16) _g -= NTILE*16; \
    const char* _b = sel3(Bb0, Bb1, Bb2, _g >> 4); const int _w = (_g & 15) * 128; \
    async16(_b + bOf##h##0 + _w, smem + 65536 + (buf)*32768 + (h)*16384 + wv*1024); \
    async16(_b + bOf##h##1 + _w, smem + 65536 + (buf)*32768 + (h)*16384 + 8192 + wv*1024); \
} while(0)

#define ITERBODY(GB) \
    const int g1 = (GB) + 2*it + 1, g2 = (GB) + 2*it + 2, g3 = (GB) + 2*it + 3; \
    /* p1 */ LDA8(0, 0); LDB4(0, 0); STGA(1, g1, 1); \
    BAR(); WAITDS(); __builtin_amdgcn_s_setprio(1); MFMAQ(0, 0); \
    __builtin_amdgcn_s_setprio(0); BAR(); \
    /* p2 */ LDB4(2, 0); STGA(0, g2, 0); \
    BAR(); WAITDS(); __builtin_amdgcn_s_setprio(1); MFMAQ(0, 2); \
    __builtin_amdgcn_s_setprio(0); BAR(); \
    /* p3 */ LDA8(4, 0); STGB(0, g2, 0); \
    BAR(); WAITDS(); __builtin_amdgcn_s_setprio(1); MFMAQ(4, 2); \
    __builtin_amdgcn_s_setprio(0); BAR(); \
    /* p4 */ STGB(1, g2, 0); \
    BAR(); WAITDS(); __builtin_amdgcn_s_setprio(1); MFMAQ(4, 0); \
    __builtin_amdgcn_s_setprio(0); VM6(); BAR(); \
    /* p5 */ LDA8(0, 1); LDB4(0, 1); STGA(1, g2, 0); \
    BAR(); WAITDS(); __builtin_amdgcn_s_setprio(1); MFMAQ(0, 0); \
    __builtin_amdgcn_s_setprio(0); BAR(); \
    /* p6 */ LDB4(2, 1); STGA(0, g3, 1); \
    BAR(); WAITDS(); __builtin_amdgcn_s_setprio(1); MFMAQ(0, 2); \
    __builtin_amdgcn_s_setprio(0); BAR(); \
    /* p7 */ LDA8(4, 1); STGB(0, g3, 1); \
    BAR(); WAITDS(); __builtin_amdgcn_s_setprio(1); MFMAQ(4, 2); \
    __builtin_amdgcn_s_setprio(0); BAR(); \
    /* p8 */ STGB(1, g3, 1); \
    BAR(); WAITDS(); __builtin_amdgcn_s_setprio(1); MFMAQ(4, 0); \
    __builtin_amdgcn_s_setprio(0); VM6(); BAR();

// register->global epilogue (no LDS, no barriers); zeroes acc for next tile
template<int EPI>
__device__ __forceinline__ void gemm_epilogue(
    floatx4 (&acc)[8][4], const float (&bv)[4],
    int mBase, int nBase, int wm, int wn, int lr, int quad,
    ushort* __restrict__ q_out, ushort* __restrict__ kT_out,
    ushort* __restrict__ vT_out, float* __restrict__ f_out)
{
    if (EPI == 0) {
        const float inv_scale = 0.35355339059327373f;  // 1/64^0.25
        const int seg = nBase >> 10;                   // 0=q, 1=k, 2=v
        if (seg == 0) {
            #pragma unroll
            for (int nf = 0; nf < 4; nf++) {
                const int c = nBase + wn * 64 + nf * 16 + lr;
                #pragma unroll
                for (int mf = 0; mf < 8; mf++)
                    #pragma unroll
                    for (int i = 0; i < 4; i++) {
                        const int t = mBase + wm * 128 + mf * 16 + quad * 4 + i;
                        q_out[(size_t)t * C_ + c] =
                            f2bf(feature_map((acc[mf][nf][i] + bv[nf]) * inv_scale));
                    }
            }
        } else {
            ushort* dstT = (seg == 1) ? kT_out : vT_out;
            #pragma unroll
            for (int nf = 0; nf < 4; nf++) {
                const int c = (nBase + wn * 64 + nf * 16 + lr) & 1023;
                #pragma unroll
                for (int mf = 0; mf < 8; mf++) {
                    float v0 = acc[mf][nf][0] + bv[nf], v1 = acc[mf][nf][1] + bv[nf];
                    float v2 = acc[mf][nf][2] + bv[nf], v3 = acc[mf][nf][3] + bv[nf];
                    if (seg == 1) {
                        v0 = feature_map(v0 * inv_scale); v1 = feature_map(v1 * inv_scale);
                        v2 = feature_map(v2 * inv_scale); v3 = feature_map(v3 * inv_scale);
                    }
                    const int tt = mBase + wm * 128 + mf * 16 + quad * 4;
                    *(ushort4*)&dstT[(size_t)c * BT_ + tt] =
                        make_ushort4(f2bf(v0), f2bf(v1), f2bf(v2), f2bf(v3));
                }
            }
        }
    } else {
        #pragma unroll
        for (int nf = 0; nf < 4; nf++) {
            const int c = nBase + wn * 64 + nf * 16 + lr;
            #pragma unroll
            for (int mf = 0; mf < 8; mf++)
                #pragma unroll
                for (int i = 0; i < 4; i++) {
                    const int row = mBase + wm * 128 + mf * 16 + quad * 4 + i;
                    f_out[(size_t)row * C_ + c] = acc[mf][nf][i] + bv[nf];
                }
        }
    }
    #pragma unroll
    for (int i = 0; i < 8; i++)
        #pragma unroll
        for (int j = 0; j < 4; j++) acc[i][j] = (floatx4)0.0f;
}

template<int EPI, int NBX, int NTILE>
__global__ __launch_bounds__(512, 2)
void gemm256_8ph(const ushort* __restrict__ A, const ushort* __restrict__ Bm,
                 const float* __restrict__ bias,
                 ushort* __restrict__ q_out, ushort* __restrict__ kT_out,
                 ushort* __restrict__ vT_out, float* __restrict__ f_out)
{
    __shared__ __align__(16) unsigned char smem[131072];

    const int tid = threadIdx.x;
    const int wv = tid >> 6, l = tid & 63;
    const int wm = wv >> 2, wn = wv & 3;
    const int lr = l & 15, quad = l >> 4;

    // logical tiles: blockIdx + q*gridDim, XCD-swizzled over the full set
    int mB0, mB1, mB2, nB0, nB1, nB2;
    {
        const int tot = (int)gridDim.x * NTILE, cpx = tot >> 3;
        int lg0 = blockIdx.x;
        int w0 = (lg0 & 7) * cpx + (lg0 >> 3);
        mB0 = (w0 / NBX) * 256; nB0 = (w0 % NBX) * 256;
        if (NTILE > 1) {
            int lg1 = blockIdx.x + (int)gridDim.x;
            int w1 = (lg1 & 7) * cpx + (lg1 >> 3);
            mB1 = (w1 / NBX) * 256; nB1 = (w1 % NBX) * 256;
            int lg2 = blockIdx.x + 2 * (int)gridDim.x;
            int w2 = (lg2 & 7) * cpx + (lg2 >> 3);
            mB2 = (w2 / NBX) * 256; nB2 = (w2 % NBX) * 256;
        } else { mB1 = mB0; nB1 = nB0; mB2 = mB0; nB2 = nB0; }
    }
    const char* Ab0 = (const char*)(A + (size_t)mB0 * C_);
    const char* Ab1 = (const char*)(A + (size_t)mB1 * C_);
    const char* Ab2 = (const char*)(A + (size_t)mB2 * C_);
    const char* Bb0 = (const char*)(Bm + (size_t)nB0 * C_);
    const char* Bb1 = (const char*)(Bm + (size_t)nB1 * C_);
    const char* Bb2 = (const char*)(Bm + (size_t)nB2 * C_);

    // preload bias (keeps epilogues free of VMEM reads)
    float bv0[4], bv1[4], bv2[4];
    #pragma unroll
    for (int nf = 0; nf < 4; nf++) {
        bv0[nf] = bias[nB0 + wn * 64 + nf * 16 + lr];
        bv1[nf] = (NTILE > 1) ? bias[nB1 + wn * 64 + nf * 16 + lr] : bv0[nf];
        bv2[nf] = (NTILE > 1) ? bias[nB2 + wn * 64 + nf * 16 + lr] : bv0[nf];
    }

    // staging source offsets (swizzled global src, linear LDS dest)
    const int s0 = tid >> 3;
    const int cb = ((tid & 7) * 16) ^ ((s0 & 7) << 4);
    const int aOf00 = (s0)       * 2048 + cb;   // A h=0 half0: row s0
    const int aOf01 = (128 + s0) * 2048 + cb;   // A h=0 half1
    const int aOf10 = (64 + s0)  * 2048 + cb;   // A h=1 half0
    const int aOf11 = (192 + s0) * 2048 + cb;   // A h=1 half1
    const int bq    = (s0 >> 5) * 64 + (s0 & 31);
    const int bOf00 = (bq)       * 2048 + cb;
    const int bOf01 = (bq + 128) * 2048 + cb;
    const int bOf10 = (bq + 32)  * 2048 + cb;
    const int bOf11 = (bq + 160) * 2048 + cb;

    // ds_read fragment addressing (swizzled)
    const int aRowB = (wm * 64 + lr) * 128;
    const int bRowB = (wn * 32 + lr) * 128;
    const int cks0 = (quad * 16) ^ ((lr & 7) << 4);
    const int cks1 = 64 ^ cks0;

    floatx4 acc[8][4];
    #pragma unroll
    for (int i = 0; i < 8; i++)
        #pragma unroll
        for (int j = 0; j < 4; j++) acc[i][j] = (floatx4)0.0f;
    short8 aR[4][2], bR[4][2];

    // prologue: 7 half-tiles, keep 3 in flight
    STGA(0, 0, 0);   // A0(0)
    STGB(0, 0, 0);   // B0(0)
    STGB(1, 0, 0);   // B1(0)
    STGA(1, 0, 0);   // A1(0)
    STGA(0, 1, 1);   // A0(1)
    STGB(0, 1, 1);   // B0(1)
    STGB(1, 1, 1);   // B1(1)
    asm volatile("s_waitcnt vmcnt(6)" ::: "memory");
    __builtin_amdgcn_sched_barrier(0);
    BAR();

    #pragma unroll 1
    for (int it = 0; it < 8; ++it) { ITERBODY(0) }
    gemm_epilogue<EPI>(acc, bv0, mB0, nB0, wm, wn, lr, quad,
                       q_out, kT_out, vT_out, f_out);
    if (NTILE > 1) {
        #pragma unroll 1
        for (int it = 0; it < 8; ++it) { ITERBODY(16) }
        gemm_epilogue<EPI>(acc, bv1, mB1, nB1, wm, wn, lr, quad,
                           q_out, kT_out, vT_out, f_out);
        #pragma unroll 1
        for (int it = 0; it < 8; ++it) { ITERBODY(32) }
        gemm_epilogue<EPI>(acc, bv2, mB2, nB2, wm, wn, lr, quad,
                           q_out, kT_out, vT_out, f_out);
    }
    asm volatile("s_waitcnt vmcnt(0)" ::: "memory");   // drain wrap-staged loads
}

// ---------------------------------------------------------------------------
// K2: kv[b,h][d][m] += sum_t km[t][d]*v[t][m]. No LDS; fragments straight from
//     row-major kmT/vT; grid (tsplit=8, b*h=64).
// ---------------------------------------------------------------------------
__global__ __launch_bounds__(256)
void kv_accum_kernel(const ushort* __restrict__ kmT, const ushort* __restrict__ vT,
                     float* __restrict__ kv)
{
    const int tid = threadIdx.x;
    const int w = tid >> 6, l = tid & 63;
    const int wm = w >> 1, wn = w & 1;
    const int lr = l & 15, quad = l >> 4;
    const int bh = blockIdx.y;                  // b*16 + h
    const int b = bh >> 4, h = bh & 15;
    const size_t t0 = (size_t)b * T_ + (size_t)blockIdx.x * 512;

    const ushort* Ar = kmT + (size_t)(h * 64 + wm * 32 + lr) * BT_ + t0 + quad * 8;
    const ushort* Br = vT  + (size_t)(h * 64 + wn * 32 + lr) * BT_ + t0 + quad * 8;

    floatx4 acc[2][2];
    #pragma unroll
    for (int i = 0; i < 2; i++)
        #pragma unroll
        for (int j = 0; j < 2; j++) acc[i][j] = (floatx4)0.0f;

    #pragma unroll 8
    for (int tt = 0; tt < 512; tt += 32) {
        const short8 af0 = *(const short8*)&Ar[tt];
        const short8 af1 = *(const short8*)&Ar[(size_t)16 * BT_ + tt];
        const short8 bf0 = *(const short8*)&Br[tt];
        const short8 bf1 = *(const short8*)&Br[(size_t)16 * BT_ + tt];
        acc[0][0] = __builtin_amdgcn_mfma_f32_16x16x32_bf16(af0, bf0, acc[0][0], 0, 0, 0);
        acc[0][1] = __builtin_amdgcn_mfma_f32_16x16x32_bf16(af0, bf1, acc[0][1], 0, 0, 0);
        acc[1][0] = __builtin_amdgcn_mfma_f32_16x16x32_bf16(af1, bf0, acc[1][0], 0, 0, 0);
        acc[1][1] = __builtin_amdgcn_mfma_f32_16x16x32_bf16(af1, bf1, acc[1][1], 0, 0, 0);
    }

    float* kvb = kv + (size_t)bh * (D_ * D_);
    #pragma unroll
    for (int i = 0; i < 2; i++)
        #pragma unroll
        for (int j = 0; j < 2; j++)
            #pragma unroll
            for (int r = 0; r < 4; r++) {
                const int d = wm * 32 + i * 16 + quad * 4 + r;
                const int m = wn * 32 + j * 16 + lr;
                atomicAdd(&kvb[d * 64 + m], acc[i][j][r]);
            }
}

// ---------------------------------------------------------------------------
// K3: out[t][m] = (sum_d qm[t][d] * kv[d][m]) / (z[t]+1e-6), per head.
// ---------------------------------------------------------------------------
__global__ __launch_bounds__(256)
void pv_kernel(const ushort* __restrict__ qm, const float* __restrict__ kv,
               ushort* __restrict__ attn)
{
    __shared__ ushort kvs[64 * 72];             // kvs[m][d] = kv[d][m], bf16
    const int tid = threadIdx.x;
    const int w = tid >> 6, l = tid & 63;
    const int lr = l & 15, quad = l >> 4;
    const int h = blockIdx.x;
    const int tBase = blockIdx.y * 256;
    const int b = tBase >> 12;

    const float* kvg = kv + ((size_t)b * H_ + h) * (D_ * D_);
    #pragma unroll
    for (int e = 0; e < 4; e++) {
        const int flat = (e * 256 + tid) * 4;
        const float4 vv = *(const float4*)&kvg[flat];
        const int d = flat >> 6, m = flat & 63;
        kvs[(m + 0) * 72 + d] = f2bf(vv.x);
        kvs[(m + 1) * 72 + d] = f2bf(vv.y);
        kvs[(m + 2) * 72 + d] = f2bf(vv.z);
        kvs[(m + 3) * 72 + d] = f2bf(vv.w);
    }
    __syncthreads();

    const int tw = tBase + w * 64;

    floatx4 acc[4][4];                          // [mf][tf]: C row=m, col=t
    #pragma unroll
    for (int i = 0; i < 4; i++)
        #pragma unroll
        for (int j = 0; j < 4; j++) acc[i][j] = (floatx4)0.0f;

    float zp[4] = {0.0f, 0.0f, 0.0f, 0.0f};

    #pragma unroll
    for (int kk = 0; kk < 2; kk++) {
        short8 bf[4];
        #pragma unroll
        for (int tf = 0; tf < 4; tf++) {
            bf[tf] = *(const short8*)&qm[(size_t)(tw + tf * 16 + lr) * C_
                                         + h * 64 + kk * 32 + quad * 8];
            #pragma unroll
            for (int j = 0; j < 8; j++) zp[tf] += bf2f((unsigned short)bf[tf][j]);
        }
        short8 af[4];
        #pragma unroll
        for (int mf = 0; mf < 4; mf++)
            af[mf] = *(const short8*)&kvs[(mf * 16 + lr) * 72 + kk * 32 + quad * 8];
        #pragma unroll
        for (int mf = 0; mf < 4; mf++)
            #pragma unroll
            for (int tf = 0; tf < 4; tf++)
                acc[mf][tf] = __builtin_amdgcn_mfma_f32_16x16x32_bf16(
                    af[mf], bf[tf], acc[mf][tf], 0, 0, 0);
    }

    #pragma unroll
    for (int tf = 0; tf < 4; tf++) {
        zp[tf] += __shfl_xor(zp[tf], 16);
        zp[tf] += __shfl_xor(zp[tf], 32);
    }

    #pragma unroll
    for (int tf = 0; tf < 4; tf++) {
        const int t = tw + tf * 16 + lr;
        const float inv = 1.0f / (zp[tf] + 1e-6f);
        #pragma unroll
        for (int mf = 0; mf < 4; mf++) {
            const int m = mf * 16 + quad * 4;
            *(ushort4*)&attn[(size_t)t * C_ + h * 64 + m] =
                make_ushort4(f2bf(acc[mf][tf][0] * inv), f2bf(acc[mf][tf][1] * inv),
                             f2bf(acc[mf][tf][2] * inv), f2bf(acc[mf][tf][3] * inv));
        }
    }
}

// ---------------------------------------------------------------------------
// Workspace map:
//   ws:    xb 33.5M (aliased as attn after QKV) | WqkvT 6.3M | WoutT 2M |
//          vT 33.5M | kv 1M
//   d_out: qm 33.5M | kmT 33.5M   (both dead before outproj writes out)
// ---------------------------------------------------------------------------
extern "C" void kernel_launch(void* const* d_in, const int* in_sizes, int n_in,
                              void* d_out, int out_size, void* d_ws, size_t ws_size,
                              hipStream_t stream)
{
    const float* x    = (const float*)d_in[0];
    const float* Wqkv = (const float*)d_in[1];
    const float* bqkv = (const float*)d_in[2];
    const float* Wout = (const float*)d_in[3];
    const float* bout = (const float*)d_in[4];
    float* out = (float*)d_out;

    char* ws = (char*)d_ws;
    ushort* xb     = (ushort*)ws;                       // 33,554,432 B
    ushort* WqkvT  = (ushort*)(ws + 33554432);          //  6,291,456 B
    ushort* WoutT  = (ushort*)(ws + 39845888);          //  2,097,152 B
    ushort* vT     = (ushort*)(ws + 41943040);          // 33,554,432 B
    float*  kv     = (float*) (ws + 75497472);          //  1,048,576 B
    ushort* attn   = (ushort*)ws;                       // alias of xb
    ushort* qm     = (ushort*)d_out;                    // scratch in d_out
    ushort* kmT    = (ushort*)((char*)d_out + 33554432);

    hipMemsetAsync(kv, 0, (size_t)B_ * H_ * D_ * D_ * sizeof(float), stream);

    convert_x_kernel<<<(BT_ * C_ / 8) / 256, 256, 0, stream>>>((const float4*)x, xb);
    transpose_bf16_kernel<<<dim3(3 * C_ / 32, C_ / 32), 256, 0, stream>>>(Wqkv, WqkvT, C_, 3 * C_);
    transpose_bf16_kernel<<<dim3(C_ / 32, C_ / 32), 256, 0, stream>>>(Wout, WoutT, C_, C_);

    gemm256_8ph<0, 12, 3><<<dim3(256), 512, 0, stream>>>(
        xb, WqkvT, bqkv, qm, kmT, vT, nullptr);
    kv_accum_kernel<<<dim3(8, B_ * H_), 256, 0, stream>>>(kmT, vT, kv);
    pv_kernel<<<dim3(H_, BT_ / 256), 256, 0, stream>>>(qm, kv, attn);
    gemm256_8ph<1, 4, 1><<<dim3(256), 512, 0, stream>>>(
        attn, WoutT, bout, nullptr, nullptr, nullptr, out);
}

// Round 5
// 307.787 us; speedup vs baseline: 1.2173x; 1.0141x over previous
//
#include <hip/hip_runtime.h>
#include <hip/hip_bf16.h>
#include <math.h>

#define B_ 4
#define T_ 4096
#define H_ 16
#define D_ 64
#define C_ 1024
#define BT_ (B_*T_)

using short8  = __attribute__((ext_vector_type(8))) short;
using floatx4 = __attribute__((ext_vector_type(4))) float;

__device__ __forceinline__ float feature_map(float x) {
    return x > 0.0f ? x + 1.0f : __expf(x);   // elu(x)+1
}
__device__ __forceinline__ unsigned short f2bf(float x) {
    union { __hip_bfloat16 b; unsigned short u; } c;
    c.b = __float2bfloat16(x);                 // RNE
    return c.u;
}
__device__ __forceinline__ void async16(const void* g, void* l) {
    __builtin_amdgcn_global_load_lds(
        (const __attribute__((address_space(1))) void*)g,
        (__attribute__((address_space(3))) void*)l, 16, 0, 0);
}
__device__ __forceinline__ const char* sel3(const char* a0, const char* a1,
                                            const char* a2, int t) {
    return t == 0 ? a0 : (t == 1 ? a1 : a2);
}

// ---------------------------------------------------------------------------
// K0a: x fp32 -> bf16 (grid-stride, 2048 blocks, 16B loads+stores)
// ---------------------------------------------------------------------------
__global__ __launch_bounds__(256)
void convert_x_kernel(const float4* __restrict__ x, ushort* __restrict__ xb)
{
    const size_t n = (size_t)BT_ * C_ / 8;
    for (size_t i = (size_t)blockIdx.x * 256 + threadIdx.x; i < n;
         i += (size_t)2048 * 256) {
        const float4 a = x[2 * i], b = x[2 * i + 1];
        short8 r;
        r[0] = (short)f2bf(a.x); r[1] = (short)f2bf(a.y);
        r[2] = (short)f2bf(a.z); r[3] = (short)f2bf(a.w);
        r[4] = (short)f2bf(b.x); r[5] = (short)f2bf(b.y);
        r[6] = (short)f2bf(b.z); r[7] = (short)f2bf(b.w);
        *reinterpret_cast<short8*>(&xb[i * 8]) = r;
    }
}

// ---------------------------------------------------------------------------
// K0b: W[K][N] fp32 -> WT[N][K] bf16
// ---------------------------------------------------------------------------
__global__ __launch_bounds__(256)
void transpose_bf16_kernel(const float* __restrict__ W, ushort* __restrict__ WT,
                           int K, int N)
{
    __shared__ float t[32][33];
    const int n0 = blockIdx.x * 32, k0 = blockIdx.y * 32;
    const int r = threadIdx.x >> 5, c = threadIdx.x & 31;
    #pragma unroll
    for (int i = 0; i < 4; i++)
        t[r + 8 * i][c] = W[(size_t)(k0 + r + 8 * i) * N + n0 + c];
    __syncthreads();
    #pragma unroll
    for (int i = 0; i < 4; i++)
        WT[(size_t)(n0 + r + 8 * i) * K + k0 + c] = f2bf(t[c][r + 8 * i]);
}

// ---------------------------------------------------------------------------
// 256x256x(K=1024) bf16 8-phase GEMM body (T1+T2+T3+T4+T5), B^T operands,
// persistent NTILE chaining. EPI 0: QKV epilogue (q'=fm/z via shfl-z, natural;
// k^T fm / v^T transposed). EPI 1: +bias fp32 out, per-b B panel.
// ---------------------------------------------------------------------------
#define BAR()    __builtin_amdgcn_s_barrier()
#define WAITDS() do { asm volatile("s_waitcnt lgkmcnt(0)" ::: "memory"); \
                      __builtin_amdgcn_sched_barrier(0); } while(0)
#define VM6()    do { asm volatile("s_waitcnt vmcnt(6)" ::: "memory"); \
                      __builtin_amdgcn_sched_barrier(0); } while(0)

#define LDA(slot, mf, ks, buf) \
    aR[slot][ks] = *(const short8*)(smem + (buf)*32768 + ((mf)>>2)*16384 + \
                                    aRowB + ((mf)&3)*2048 + cks##ks)
#define LDB(nf, ks, buf) \
    bR[nf][ks] = *(const short8*)(smem + 65536 + (buf)*32768 + ((nf)>>1)*16384 + \
                                  bRowB + ((nf)&1)*2048 + cks##ks)
#define LDA8(MB, BUF) do { \
    LDA(0, MB+0, 0, BUF); LDA(0, MB+0, 1, BUF); \
    LDA(1, MB+1, 0, BUF); LDA(1, MB+1, 1, BUF); \
    LDA(2, MB+2, 0, BUF); LDA(2, MB+2, 1, BUF); \
    LDA(3, MB+3, 0, BUF); LDA(3, MB+3, 1, BUF); } while(0)
#define LDB4(NF, BUF) do { \
    LDB(NF+0, 0, BUF); LDB(NF+0, 1, BUF); \
    LDB(NF+1, 0, BUF); LDB(NF+1, 1, BUF); } while(0)

#define MM(mf, nf, ks, slot) \
    acc[mf][nf] = __builtin_amdgcn_mfma_f32_16x16x32_bf16( \
        aR[slot][ks], bR[nf][ks], acc[mf][nf], 0, 0, 0)
#define MFMAQ(MB, NF) do { \
    MM(MB+0,NF+0,0,0); MM(MB+1,NF+0,0,1); MM(MB+2,NF+0,0,2); MM(MB+3,NF+0,0,3); \
    MM(MB+0,NF+1,0,0); MM(MB+1,NF+1,0,1); MM(MB+2,NF+1,0,2); MM(MB+3,NF+1,0,3); \
    MM(MB+0,NF+0,1,0); MM(MB+1,NF+0,1,1); MM(MB+2,NF+0,1,2); MM(MB+3,NF+0,1,3); \
    MM(MB+0,NF+1,1,0); MM(MB+1,NF+1,1,1); MM(MB+2,NF+1,1,2); MM(MB+3,NF+1,1,3); \
} while(0)

#define STGA(h, G, buf) do { int _g = (G); if (_g >= NTILE*16) _g -= NTILE*16; \
    const char* _b = sel3(Ab0, Ab1, Ab2, _g >> 4); const int _w = (_g & 15) * 128; \
    async16(_b + aOf##h##0 + _w, smem + (buf)*32768 + (h)*16384 + wv*1024); \
    async16(_b + aOf##h##1 + _w, smem + (buf)*32768 + (h)*16384 + 8192 + wv*1024); \
} while(0)
#define STGB(h, G, buf) do { int _g = (G); if (_g >= NTILE*16) _g -= NTILE*16; \
    const char* _b = sel3(Bb0, Bb1, Bb2, _g >> 4); const int _w = (_g & 15) * 128; \
    async16(_b + bOf##h##0 + _w, smem + 65536 + (buf)*32768 + (h)*16384 + wv*1024); \
    async16(_b + bOf##h##1 + _w, smem + 65536 + (buf)*32768 + (h)*16384 + 8192 + wv*1024); \
} while(0)

#define ITERBODY(GB) \
    const int g1 = (GB) + 2*it + 1, g2 = (GB) + 2*it + 2, g3 = (GB) + 2*it + 3; \
    /* p1 */ LDA8(0, 0); LDB4(0, 0); STGA(1, g1, 1); \
    BAR(); WAITDS(); __builtin_amdgcn_s_setprio(1); MFMAQ(0, 0); \
    __builtin_amdgcn_s_setprio(0); BAR(); \
    /* p2 */ LDB4(2, 0); STGA(0, g2, 0); \
    BAR(); WAITDS(); __builtin_amdgcn_s_setprio(1); MFMAQ(0, 2); \
    __builtin_amdgcn_s_setprio(0); BAR(); \
    /* p3 */ LDA8(4, 0); STGB(0, g2, 0); \
    BAR(); WAITDS(); __builtin_amdgcn_s_setprio(1); MFMAQ(4, 2); \
    __builtin_amdgcn_s_setprio(0); BAR(); \
    /* p4 */ STGB(1, g2, 0); \
    BAR(); WAITDS(); __builtin_amdgcn_s_setprio(1); MFMAQ(4, 0); \
    __builtin_amdgcn_s_setprio(0); VM6(); BAR(); \
    /* p5 */ LDA8(0, 1); LDB4(0, 1); STGA(1, g2, 0); \
    BAR(); WAITDS(); __builtin_amdgcn_s_setprio(1); MFMAQ(0, 0); \
    __builtin_amdgcn_s_setprio(0); BAR(); \
    /* p6 */ LDB4(2, 1); STGA(0, g3, 1); \
    BAR(); WAITDS(); __builtin_amdgcn_s_setprio(1); MFMAQ(0, 2); \
    __builtin_amdgcn_s_setprio(0); BAR(); \
    /* p7 */ LDA8(4, 1); STGB(0, g3, 1); \
    BAR(); WAITDS(); __builtin_amdgcn_s_setprio(1); MFMAQ(4, 2); \
    __builtin_amdgcn_s_setprio(0); BAR(); \
    /* p8 */ STGB(1, g3, 1); \
    BAR(); WAITDS(); __builtin_amdgcn_s_setprio(1); MFMAQ(4, 0); \
    __builtin_amdgcn_s_setprio(0); VM6(); BAR();

// register->global epilogue; zeroes acc for next tile
template<int EPI>
__device__ __forceinline__ void gemm_epilogue(
    floatx4 (&acc)[8][4], const float (&bv)[4],
    int mBase, int nBase, int wm, int wn, int lr, int quad,
    ushort* __restrict__ q_out, ushort* __restrict__ kT_out,
    ushort* __restrict__ vT_out, float* __restrict__ f_out)
{
    if (EPI == 0) {
        const float inv_scale = 0.35355339059327373f;  // 1/64^0.25
        const int seg = nBase >> 10;                   // 0=q, 1=k, 2=v
        if (seg == 0) {
            // q' = fm(q)/(z+1e-6); wave wn owns one full head's 64 columns,
            // z = row-sum over those 64 c = 4-frag sum + shfl_xor over lr.
            #pragma unroll
            for (int mf = 0; mf < 8; mf++)
                #pragma unroll
                for (int i = 0; i < 4; i++) {
                    float f0 = feature_map((acc[mf][0][i] + bv[0]) * inv_scale);
                    float f1 = feature_map((acc[mf][1][i] + bv[1]) * inv_scale);
                    float f2 = feature_map((acc[mf][2][i] + bv[2]) * inv_scale);
                    float f3 = feature_map((acc[mf][3][i] + bv[3]) * inv_scale);
                    float z = f0 + f1 + f2 + f3;
                    z += __shfl_xor(z, 1); z += __shfl_xor(z, 2);
                    z += __shfl_xor(z, 4); z += __shfl_xor(z, 8);
                    const float inv = 1.0f / (z + 1e-6f);
                    const int t = mBase + wm * 128 + mf * 16 + quad * 4 + i;
                    const int cbase = nBase + wn * 64 + lr;
                    q_out[(size_t)t * C_ + cbase]      = f2bf(f0 * inv);
                    q_out[(size_t)t * C_ + cbase + 16] = f2bf(f1 * inv);
                    q_out[(size_t)t * C_ + cbase + 32] = f2bf(f2 * inv);
                    q_out[(size_t)t * C_ + cbase + 48] = f2bf(f3 * inv);
                }
        } else {
            ushort* dstT = (seg == 1) ? kT_out : vT_out;
            #pragma unroll
            for (int nf = 0; nf < 4; nf++) {
                const int c = (nBase + wn * 64 + nf * 16 + lr) & 1023;
                #pragma unroll
                for (int mf = 0; mf < 8; mf++) {
                    float v0 = acc[mf][nf][0] + bv[nf], v1 = acc[mf][nf][1] + bv[nf];
                    float v2 = acc[mf][nf][2] + bv[nf], v3 = acc[mf][nf][3] + bv[nf];
                    if (seg == 1) {
                        v0 = feature_map(v0 * inv_scale); v1 = feature_map(v1 * inv_scale);
                        v2 = feature_map(v2 * inv_scale); v3 = feature_map(v3 * inv_scale);
                    }
                    const int tt = mBase + wm * 128 + mf * 16 + quad * 4;
                    *(ushort4*)&dstT[(size_t)c * BT_ + tt] =
                        make_ushort4(f2bf(v0), f2bf(v1), f2bf(v2), f2bf(v3));
                }
            }
        }
    } else {
        #pragma unroll
        for (int nf = 0; nf < 4; nf++) {
            const int c = nBase + wn * 64 + nf * 16 + lr;
            #pragma unroll
            for (int mf = 0; mf < 8; mf++)
                #pragma unroll
                for (int i = 0; i < 4; i++) {
                    const int row = mBase + wm * 128 + mf * 16 + quad * 4 + i;
                    f_out[(size_t)row * C_ + c] = acc[mf][nf][i] + bv[nf];
                }
        }
    }
    #pragma unroll
    for (int i = 0; i < 8; i++)
        #pragma unroll
        for (int j = 0; j < 4; j++) acc[i][j] = (floatx4)0.0f;
}

template<int EPI, int NBX, int NTILE>
__device__ __forceinline__ void gemm_body(
    const ushort* __restrict__ A, const ushort* __restrict__ Bm,
    const float* __restrict__ bias,
    ushort* __restrict__ q_out, ushort* __restrict__ kT_out,
    ushort* __restrict__ vT_out, float* __restrict__ f_out)
{
    __shared__ __align__(16) unsigned char smem[131072];

    const int tid = threadIdx.x;
    const int wv = tid >> 6, l = tid & 63;
    const int wm = wv >> 2, wn = wv & 3;
    const int lr = l & 15, quad = l >> 4;

    int mB0, mB1, mB2, nB0, nB1, nB2;
    {
        const int tot = (int)gridDim.x * NTILE, cpx = tot >> 3;
        int lg0 = blockIdx.x;
        int w0 = (lg0 & 7) * cpx + (lg0 >> 3);
        mB0 = (w0 / NBX) * 256; nB0 = (w0 % NBX) * 256;
        if (NTILE > 1) {
            int lg1 = blockIdx.x + (int)gridDim.x;
            int w1 = (lg1 & 7) * cpx + (lg1 >> 3);
            mB1 = (w1 / NBX) * 256; nB1 = (w1 % NBX) * 256;
            int lg2 = blockIdx.x + 2 * (int)gridDim.x;
            int w2 = (lg2 & 7) * cpx + (lg2 >> 3);
            mB2 = (w2 / NBX) * 256; nB2 = (w2 % NBX) * 256;
        } else { mB1 = mB0; nB1 = nB0; mB2 = mB0; nB2 = nB0; }
    }
    // EPI=1: B panel differs per batch b = mBase>>12 (KWT[b])
    const size_t bOffB = (EPI == 1) ? (size_t)(mB0 >> 12) * ((size_t)C_ * C_) : 0;
    const char* Ab0 = (const char*)(A + (size_t)mB0 * C_);
    const char* Ab1 = (const char*)(A + (size_t)mB1 * C_);
    const char* Ab2 = (const char*)(A + (size_t)mB2 * C_);
    const char* Bb0 = (const char*)(Bm + bOffB + (size_t)nB0 * C_);
    const char* Bb1 = (const char*)(Bm + bOffB + (size_t)nB1 * C_);
    const char* Bb2 = (const char*)(Bm + bOffB + (size_t)nB2 * C_);

    float bv0[4], bv1[4], bv2[4];
    #pragma unroll
    for (int nf = 0; nf < 4; nf++) {
        bv0[nf] = bias[nB0 + wn * 64 + nf * 16 + lr];
        bv1[nf] = (NTILE > 1) ? bias[nB1 + wn * 64 + nf * 16 + lr] : bv0[nf];
        bv2[nf] = (NTILE > 1) ? bias[nB2 + wn * 64 + nf * 16 + lr] : bv0[nf];
    }

    const int s0 = tid >> 3;
    const int cb = ((tid & 7) * 16) ^ ((s0 & 7) << 4);
    const int aOf00 = (s0)       * 2048 + cb;
    const int aOf01 = (128 + s0) * 2048 + cb;
    const int aOf10 = (64 + s0)  * 2048 + cb;
    const int aOf11 = (192 + s0) * 2048 + cb;
    const int bq    = (s0 >> 5) * 64 + (s0 & 31);
    const int bOf00 = (bq)       * 2048 + cb;
    const int bOf01 = (bq + 128) * 2048 + cb;
    const int bOf10 = (bq + 32)  * 2048 + cb;
    const int bOf11 = (bq + 160) * 2048 + cb;

    const int aRowB = (wm * 64 + lr) * 128;
    const int bRowB = (wn * 32 + lr) * 128;
    const int cks0 = (quad * 16) ^ ((lr & 7) << 4);
    const int cks1 = 64 ^ cks0;

    floatx4 acc[8][4];
    #pragma unroll
    for (int i = 0; i < 8; i++)
        #pragma unroll
        for (int j = 0; j < 4; j++) acc[i][j] = (floatx4)0.0f;
    short8 aR[4][2], bR[4][2];

    STGA(0, 0, 0); STGB(0, 0, 0); STGB(1, 0, 0); STGA(1, 0, 0);
    STGA(0, 1, 1); STGB(0, 1, 1); STGB(1, 1, 1);
    asm volatile("s_waitcnt vmcnt(6)" ::: "memory");
    __builtin_amdgcn_sched_barrier(0);
    BAR();

    #pragma unroll 1
    for (int it = 0; it < 8; ++it) { ITERBODY(0) }
    gemm_epilogue<EPI>(acc, bv0, mB0, nB0, wm, wn, lr, quad,
                       q_out, kT_out, vT_out, f_out);
    if (NTILE > 1) {
        #pragma unroll 1
        for (int it = 0; it < 8; ++it) { ITERBODY(16) }
        gemm_epilogue<EPI>(acc, bv1, mB1, nB1, wm, wn, lr, quad,
                           q_out, kT_out, vT_out, f_out);
        #pragma unroll 1
        for (int it = 0; it < 8; ++it) { ITERBODY(32) }
        gemm_epilogue<EPI>(acc, bv2, mB2, nB2, wm, wn, lr, quad,
                           q_out, kT_out, vT_out, f_out);
    }
    asm volatile("s_waitcnt vmcnt(0)" ::: "memory");
}

__global__ __launch_bounds__(512, 2)
void qkv8_kernel(const ushort* __restrict__ A, const ushort* __restrict__ Bm,
                 const float* __restrict__ bias, ushort* __restrict__ q_out,
                 ushort* __restrict__ kT_out, ushort* __restrict__ vT_out)
{
    gemm_body<0, 12, 3>(A, Bm, bias, q_out, kT_out, vT_out, nullptr);
}

__global__ __launch_bounds__(512, 2)
void outproj8_kernel(const ushort* __restrict__ A, const ushort* __restrict__ Bm,
                     const float* __restrict__ bias, float* __restrict__ f_out)
{
    gemm_body<1, 4, 1>(A, Bm, bias, nullptr, nullptr, nullptr, f_out);
}

// ---------------------------------------------------------------------------
// K2: kv[b,h][d][m] += sum_t km[t][d]*v[t][m]. grid (tsplit=8, b*h=64).
// ---------------------------------------------------------------------------
__global__ __launch_bounds__(256)
void kv_accum_kernel(const ushort* __restrict__ kmT, const ushort* __restrict__ vT,
                     float* __restrict__ kv)
{
    const int tid = threadIdx.x;
    const int w = tid >> 6, l = tid & 63;
    const int wm = w >> 1, wn = w & 1;
    const int lr = l & 15, quad = l >> 4;
    const int bh = blockIdx.y;
    const int b = bh >> 4, h = bh & 15;
    const size_t t0 = (size_t)b * T_ + (size_t)blockIdx.x * 512;

    const ushort* Ar = kmT + (size_t)(h * 64 + wm * 32 + lr) * BT_ + t0 + quad * 8;
    const ushort* Br = vT  + (size_t)(h * 64 + wn * 32 + lr) * BT_ + t0 + quad * 8;

    floatx4 acc[2][2];
    #pragma unroll
    for (int i = 0; i < 2; i++)
        #pragma unroll
        for (int j = 0; j < 2; j++) acc[i][j] = (floatx4)0.0f;

    #pragma unroll 8
    for (int tt = 0; tt < 512; tt += 32) {
        const short8 af0 = *(const short8*)&Ar[tt];
        const short8 af1 = *(const short8*)&Ar[(size_t)16 * BT_ + tt];
        const short8 bf0 = *(const short8*)&Br[tt];
        const short8 bf1 = *(const short8*)&Br[(size_t)16 * BT_ + tt];
        acc[0][0] = __builtin_amdgcn_mfma_f32_16x16x32_bf16(af0, bf0, acc[0][0], 0, 0, 0);
        acc[0][1] = __builtin_amdgcn_mfma_f32_16x16x32_bf16(af0, bf1, acc[0][1], 0, 0, 0);
        acc[1][0] = __builtin_amdgcn_mfma_f32_16x16x32_bf16(af1, bf0, acc[1][0], 0, 0, 0);
        acc[1][1] = __builtin_amdgcn_mfma_f32_16x16x32_bf16(af1, bf1, acc[1][1], 0, 0, 0);
    }

    float* kvb = kv + (size_t)bh * (D_ * D_);
    #pragma unroll
    for (int i = 0; i < 2; i++)
        #pragma unroll
        for (int j = 0; j < 2; j++)
            #pragma unroll
            for (int r = 0; r < 4; r++) {
                const int d = wm * 32 + i * 16 + quad * 4 + r;
                const int m = wn * 32 + j * 16 + lr;
                atomicAdd(&kvb[d * 64 + m], acc[i][j][r]);
            }
}

// ---------------------------------------------------------------------------
// K3: KWT[b][c][h*64+d] = sum_m kv[b,h][d][m] * Wout[h*64+m][c]
//     (fused kv@Wout; lets outproj consume q' directly, eliminating pv).
//     grid (4 cblk, 64 bh); wave w: c-range cblk*256 + w*64; K=64 (2 MFMA ks).
// ---------------------------------------------------------------------------
__global__ __launch_bounds__(256)
void kw_kernel(const float* __restrict__ kv, const ushort* __restrict__ WoutT,
               ushort* __restrict__ KWT)
{
    const int tid = threadIdx.x;
    const int w = tid >> 6, l = tid & 63;
    const int lr = l & 15, quad = l >> 4;
    const int bh = blockIdx.y, b = bh >> 4, h = bh & 15;
    const int c0 = blockIdx.x * 256 + w * 64;

    const float* kvb = kv + (size_t)bh * (D_ * D_);

    // B-frags: rows d, k=m (kv row-major [d][m], fp32 -> bf16 in-reg)
    short8 bf[4][2];
    #pragma unroll
    for (int df = 0; df < 4; df++)
        #pragma unroll
        for (int ks = 0; ks < 2; ks++) {
            const float* src = &kvb[(df * 16 + lr) * 64 + ks * 32 + quad * 8];
            const float4 u0 = *(const float4*)src;
            const float4 u1 = *(const float4*)(src + 4);
            short8 t;
            t[0] = (short)f2bf(u0.x); t[1] = (short)f2bf(u0.y);
            t[2] = (short)f2bf(u0.z); t[3] = (short)f2bf(u0.w);
            t[4] = (short)f2bf(u1.x); t[5] = (short)f2bf(u1.y);
            t[6] = (short)f2bf(u1.z); t[7] = (short)f2bf(u1.w);
            bf[df][ks] = t;
        }

    floatx4 acc[4][4];
    #pragma unroll
    for (int i = 0; i < 4; i++)
        #pragma unroll
        for (int j = 0; j < 4; j++) acc[i][j] = (floatx4)0.0f;

    #pragma unroll
    for (int ks = 0; ks < 2; ks++) {
        short8 af[4];
        #pragma unroll
        for (int cf = 0; cf < 4; cf++)
            af[cf] = *(const short8*)&WoutT[(size_t)(c0 + cf * 16 + lr) * C_
                                            + h * 64 + ks * 32 + quad * 8];
        #pragma unroll
        for (int cf = 0; cf < 4; cf++)
            #pragma unroll
            for (int df = 0; df < 4; df++)
                acc[cf][df] = __builtin_amdgcn_mfma_f32_16x16x32_bf16(
                    af[cf], bf[df][ks], acc[cf][df], 0, 0, 0);
    }

    ushort* dst = KWT + (size_t)b * (C_ * C_);
    #pragma unroll
    for (int cf = 0; cf < 4; cf++)
        #pragma unroll
        for (int i = 0; i < 4; i++) {
            const int c = c0 + cf * 16 + quad * 4 + i;
            #pragma unroll
            for (int df = 0; df < 4; df++)
                dst[(size_t)c * C_ + h * 64 + df * 16 + lr] = f2bf(acc[cf][df][i]);
        }
}

// ---------------------------------------------------------------------------
// Workspace map:
//   ws:    xb 33.5M (-> KWT 8M after QKV) | WqkvT 6.3M | WoutT 2M |
//          qs 33.5M | kv 1M                              (= 76,546,048 B)
//   d_out: kmT 33.5M | vT 33.5M  (both dead before outproj writes out)
// ---------------------------------------------------------------------------
extern "C" void kernel_launch(void* const* d_in, const int* in_sizes, int n_in,
                              void* d_out, int out_size, void* d_ws, size_t ws_size,
                              hipStream_t stream)
{
    const float* x    = (const float*)d_in[0];
    const float* Wqkv = (const float*)d_in[1];
    const float* bqkv = (const float*)d_in[2];
    const float* Wout = (const float*)d_in[3];
    const float* bout = (const float*)d_in[4];
    float* out = (float*)d_out;

    char* ws = (char*)d_ws;
    ushort* xb     = (ushort*)ws;                       // 33,554,432 B
    ushort* WqkvT  = (ushort*)(ws + 33554432);          //  6,291,456 B
    ushort* WoutT  = (ushort*)(ws + 39845888);          //  2,097,152 B
    ushort* qs     = (ushort*)(ws + 41943040);          // 33,554,432 B (q')
    float*  kv     = (float*) (ws + 75497472);          //  1,048,576 B
    ushort* KWT    = (ushort*)ws;                       // alias xb (dead after QKV)
    ushort* kmT    = (ushort*)d_out;                    // scratch in d_out
    ushort* vT     = (ushort*)((char*)d_out + 33554432);

    hipMemsetAsync(kv, 0, (size_t)B_ * H_ * D_ * D_ * sizeof(float), stream);

    convert_x_kernel<<<2048, 256, 0, stream>>>((const float4*)x, xb);
    transpose_bf16_kernel<<<dim3(3 * C_ / 32, C_ / 32), 256, 0, stream>>>(Wqkv, WqkvT, C_, 3 * C_);
    transpose_bf16_kernel<<<dim3(C_ / 32, C_ / 32), 256, 0, stream>>>(Wout, WoutT, C_, C_);

    qkv8_kernel<<<dim3(256), 512, 0, stream>>>(xb, WqkvT, bqkv, qs, kmT, vT);
    kv_accum_kernel<<<dim3(8, B_ * H_), 256, 0, stream>>>(kmT, vT, kv);
    kw_kernel<<<dim3(4, B_ * H_), 256, 0, stream>>>(kv, WoutT, KWT);
    outproj8_kernel<<<dim3(256), 512, 0, stream>>>(qs, KWT, bout, out);
}